// Round 4
// baseline (22146.500 us; speedup 1.0000x reference)
//
#include <hip/hip_runtime.h>
#include <math.h>

// Problem constants
#define SEQ 2048
#define EMB_D 512
#define HID 512
#define NTAGS 12
#define START_TAG 10
#define STOP_TAG 11
#define NEGV (-10000.0f)
#define POISON 0xAAAAAAAAu

// fast transcendentals (v_exp_f32 + v_rcp_f32); saturate correctly at +-inf
__device__ __forceinline__ float sigf(float x) {
    return __fdividef(1.f, 1.f + __expf(-x));
}
__device__ __forceinline__ float tanh_fast(float x) {
    return 1.f - __fdividef(2.f, __expf(2.f * x) + 1.f);
}

__device__ __forceinline__ bool is_poison(float x) {
    return __float_as_uint(x) == POISON;
}

// ---------------------------------------------------------------------------
// K0: embedding gather  x0[t][e] = emb[sentence[t]][e]
// ---------------------------------------------------------------------------
__global__ void k_embed(const int* __restrict__ sent, const float* __restrict__ emb,
                        float* __restrict__ x0) {
    int t = blockIdx.x;
    int tid = threadIdx.x;  // 128 threads, 128 float4 = 512 floats
    int row = sent[t];
    const float4* src = (const float4*)(emb + (size_t)row * EMB_D);
    float4* dst = (float4*)(x0 + (size_t)t * EMB_D);
    dst[tid] = src[tid];
}

// ---------------------------------------------------------------------------
// K1/K3: fp32 GEMM  C[d][m][n] = sum_k A[m][k] * B[d][n][k] + biasA[d][n]+biasB[d][n]
// A[m][k] = (k<512 ? Af[m*512+k] : Ab[m*512+(k-512)])  (handles concat input)
// M = N = 2048 fixed, K in {512,1024}. Tile 64x64, BK=32, 256 threads, 4x4/thread.
// ---------------------------------------------------------------------------
#define BM 64
#define BN 64
#define BKT 32
#define LDT 68

__global__ __launch_bounds__(256) void k_gemm(
    const float* __restrict__ Af, const float* __restrict__ Ab,
    const float* __restrict__ B,
    const float* __restrict__ biasA, const float* __restrict__ biasB,
    float* __restrict__ C, int K) {
    const int N = 2048;
    int dir = blockIdx.z;
    const float* Bd = B + (size_t)dir * N * K;
    const float* bA = biasA + dir * N;
    const float* bB = biasB + dir * N;
    float* Cd = C + (size_t)dir * 2048 * N;
    int m0 = blockIdx.y * BM, n0 = blockIdx.x * BN;

    __shared__ float As[BKT * LDT];
    __shared__ float Bs[BKT * LDT];

    int tid = threadIdx.x;
    int lrow = tid >> 2;          // 0..63
    int lk4 = (tid & 3) * 8;      // 0,8,16,24
    int tx = tid & 15, ty = tid >> 4;

    float acc[4][4] = {};

    for (int kt = 0; kt < K; kt += BKT) {
        // load A tile (k-major in LDS)
        {
            int m = m0 + lrow;
#pragma unroll
            for (int hh = 0; hh < 2; ++hh) {
                int k = kt + lk4 + hh * 4;
                const float* src = (k < 512) ? (Af + (size_t)m * 512 + k)
                                             : (Ab + (size_t)m * 512 + (k - 512));
                float4 v = *(const float4*)src;
                int kl = lk4 + hh * 4;
                As[(kl + 0) * LDT + lrow] = v.x;
                As[(kl + 1) * LDT + lrow] = v.y;
                As[(kl + 2) * LDT + lrow] = v.z;
                As[(kl + 3) * LDT + lrow] = v.w;
            }
        }
        // load B tile
        {
            int n = n0 + lrow;
#pragma unroll
            for (int hh = 0; hh < 2; ++hh) {
                int k = kt + lk4 + hh * 4;
                float4 v = *(const float4*)(Bd + (size_t)n * K + k);
                int kl = lk4 + hh * 4;
                Bs[(kl + 0) * LDT + lrow] = v.x;
                Bs[(kl + 1) * LDT + lrow] = v.y;
                Bs[(kl + 2) * LDT + lrow] = v.z;
                Bs[(kl + 3) * LDT + lrow] = v.w;
            }
        }
        __syncthreads();
#pragma unroll
        for (int kk = 0; kk < BKT; ++kk) {
            float4 av = *(const float4*)&As[kk * LDT + ty * 4];
            float4 bv = *(const float4*)&Bs[kk * LDT + tx * 4];
            acc[0][0] += av.x * bv.x; acc[0][1] += av.x * bv.y; acc[0][2] += av.x * bv.z; acc[0][3] += av.x * bv.w;
            acc[1][0] += av.y * bv.x; acc[1][1] += av.y * bv.y; acc[1][2] += av.y * bv.z; acc[1][3] += av.y * bv.w;
            acc[2][0] += av.z * bv.x; acc[2][1] += av.z * bv.y; acc[2][2] += av.z * bv.z; acc[2][3] += av.z * bv.w;
            acc[3][0] += av.w * bv.x; acc[3][1] += av.w * bv.y; acc[3][2] += av.w * bv.z; acc[3][3] += av.w * bv.w;
        }
        __syncthreads();
    }
#pragma unroll
    for (int i = 0; i < 4; ++i) {
        int m = m0 + ty * 4 + i;
#pragma unroll
        for (int j = 0; j < 4; ++j) {
            int n = n0 + tx * 4 + j;
            Cd[(size_t)m * N + n] = acc[i][j] + bA[n] + bB[n];
        }
    }
}

// ---------------------------------------------------------------------------
// K2/K4: LSTM recurrence, one layer, both directions.
// 256 WGs x 256 threads = 1024 waves; ONE WAVE = ONE HIDDEN UNIT.
// Lane q owns an 8-wide k-slice of all 4 gate rows of its unit -> 32
// weights/thread (small enough that the allocator keeps them resident;
// 128/thread provably spills). No LDS, no __syncthreads in the loop.
// Per step: prefetch Gi -> poll own 8 h-words via coherent dwordx4 loads
// (0xAA poison = "not written") -> 32 FMAs -> shfl_xor butterfly reduce
// -> nonlinearity (all lanes, uniform) -> lane 0 publishes h with a
// relaxed agent-scope store (coherent at LLC).
// ---------------------------------------------------------------------------
__global__ __launch_bounds__(256, 1) void k_lstm(
    const float* __restrict__ Whh,  // [2][2048][512]
    const float* __restrict__ Gi,   // [2][2048][2048]  (Wih@x + bih + bhh)
    float* __restrict__ hstore)     // [2][2048][512], pre-poisoned 0xAA
{
    int wg = blockIdx.x;            // 0..255
    int dir = wg >> 7;              // 0 fwd, 1 bwd
    int wave = threadIdx.x >> 6;    // 0..3
    int q = threadIdx.x & 63;       // lane in wave
    int u = (wg & 127) * 4 + wave;  // hidden unit 0..511

    const float* Whh_d = Whh + (size_t)dir * 2048 * 512;
    const float* Gi_d = Gi + (size_t)dir * 2048 * 2048;
    float* h_d = hstore + (size_t)dir * 2048 * 512;

    // weights: wreg[g*8+j] = Whh[dir][g*512+u][q*8+j]
    float wreg[32];
#pragma unroll
    for (int g = 0; g < 4; ++g) {
        const float4* ws = (const float4*)(Whh_d + (size_t)(g * 512 + u) * 512 + q * 8);
        float4 w0 = ws[0], w1 = ws[1];
        wreg[g * 8 + 0] = w0.x; wreg[g * 8 + 1] = w0.y;
        wreg[g * 8 + 2] = w0.z; wreg[g * 8 + 3] = w0.w;
        wreg[g * 8 + 4] = w1.x; wreg[g * 8 + 5] = w1.y;
        wreg[g * 8 + 6] = w1.z; wreg[g * 8 + 7] = w1.w;
    }
#pragma unroll
    for (int j = 0; j < 32; ++j) asm volatile("" : "+v"(wreg[j]));

    float c_reg = 0.0f;

    for (int it = 0; it < 2048; ++it) {
        int t = dir ? (2047 - it) : it;

        // Gi prefetch (lanes 0..3 pick up gate q's input term) — before poll
        float gi = 0.f;
        if (q < 4) gi = Gi_d[(size_t)t * 2048 + q * 512 + u];

        float4 ha, hb;
        if (it == 0) {
            ha = make_float4(0.f, 0.f, 0.f, 0.f);
            hb = ha;
        } else {
            int tprev = dir ? (t + 1) : (t - 1);
            const float* p0 = h_d + (size_t)tprev * 512 + q * 8;
            const float* p1 = p0 + 4;
            do {
                // coherent 16B loads straight from the LLC (bypass L1/L2)
                asm volatile(
                    "global_load_dwordx4 %0, %2, off sc0 sc1\n\t"
                    "global_load_dwordx4 %1, %3, off sc0 sc1\n\t"
                    "s_waitcnt vmcnt(0)"
                    : "=&v"(ha), "=&v"(hb)
                    : "v"(p0), "v"(p1)
                    : "memory");
            } while (is_poison(ha.x) || is_poison(ha.y) || is_poison(ha.z) ||
                     is_poison(ha.w) || is_poison(hb.x) || is_poison(hb.y) ||
                     is_poison(hb.z) || is_poison(hb.w));
        }

        // 4 gate partial dots over this lane's 8-wide slice
        float acc0, acc1, acc2, acc3;
        {
            acc0 = wreg[0] * ha.x + wreg[1] * ha.y + wreg[2] * ha.z + wreg[3] * ha.w
                 + wreg[4] * hb.x + wreg[5] * hb.y + wreg[6] * hb.z + wreg[7] * hb.w;
            acc1 = wreg[8] * ha.x + wreg[9] * ha.y + wreg[10] * ha.z + wreg[11] * ha.w
                 + wreg[12] * hb.x + wreg[13] * hb.y + wreg[14] * hb.z + wreg[15] * hb.w;
            acc2 = wreg[16] * ha.x + wreg[17] * ha.y + wreg[18] * ha.z + wreg[19] * ha.w
                 + wreg[20] * hb.x + wreg[21] * hb.y + wreg[22] * hb.z + wreg[23] * hb.w;
            acc3 = wreg[24] * ha.x + wreg[25] * ha.y + wreg[26] * ha.z + wreg[27] * ha.w
                 + wreg[28] * hb.x + wreg[29] * hb.y + wreg[30] * hb.z + wreg[31] * hb.w;
        }
        // fold the precomputed input terms in before the reduce
        acc0 += (q == 0) ? gi : 0.f;
        acc1 += (q == 1) ? gi : 0.f;
        acc2 += (q == 2) ? gi : 0.f;
        acc3 += (q == 3) ? gi : 0.f;
        // butterfly reduce across the wave (all lanes end with the totals)
#pragma unroll
        for (int m = 1; m < 64; m <<= 1) {
            acc0 += __shfl_xor(acc0, m);
            acc1 += __shfl_xor(acc1, m);
            acc2 += __shfl_xor(acc2, m);
            acc3 += __shfl_xor(acc3, m);
        }

        // torch gate order: i,f,g,o = acc0,acc1,acc2,acc3 (uniform on all lanes)
        float c = sigf(acc1) * c_reg + sigf(acc0) * tanh_fast(acc2);
        float h = sigf(acc3) * tanh_fast(c);
        c_reg = c;
        if (q == 0) {
            // publish at the coherent point; the value itself is the flag
            __hip_atomic_store(h_d + (size_t)t * 512 + u, h,
                               __ATOMIC_RELAXED, __HIP_MEMORY_SCOPE_AGENT);
        }
    }
}

// ---------------------------------------------------------------------------
// K5: feats[t][tag] = sum_k concat(h1f[t],h1b[t])[k] * W_tag[tag][k] + b_tag[tag]
// one 64-thread block per t
// ---------------------------------------------------------------------------
__global__ __launch_bounds__(64) void k_feats(
    const float* __restrict__ h1,  // [2][2048][512]
    const float* __restrict__ Wt,  // [12][1024]
    const float* __restrict__ bt,  // [12]
    float* __restrict__ feats)     // [2048][12]
{
    int t = blockIdx.x;
    int lane = threadIdx.x;
    __shared__ __align__(16) float xl[1024];
    const float4* hf = (const float4*)(h1 + (size_t)t * 512);
    const float4* hb = (const float4*)(h1 + (size_t)(2048 + t) * 512);
    ((float4*)xl)[lane] = hf[lane];
    ((float4*)xl)[lane + 64] = hf[lane + 64];
    ((float4*)xl)[128 + lane] = hb[lane];
    ((float4*)xl)[128 + lane + 64] = hb[lane + 64];
    __syncthreads();
    for (int tag = 0; tag < NTAGS; ++tag) {
        const float* wrow = Wt + tag * 1024;
        float s = 0.f;
        for (int k = lane; k < 1024; k += 64) s += xl[k] * wrow[k];
#pragma unroll
        for (int off = 32; off; off >>= 1) s += __shfl_xor(s, off);
        if (lane == 0) feats[t * NTAGS + tag] = s + bt[tag];
    }
}

// ---------------------------------------------------------------------------
// K6: Viterbi forward + backtrack, single 64-thread block.
// Backpointers kept in LDS as uchar; feats prefetched in 256-step chunks.
// out[0] = path_score, out[1..2048] = best_path (as floats)
// ---------------------------------------------------------------------------
__global__ __launch_bounds__(64) void k_viterbi(
    const float* __restrict__ feats, const float* __restrict__ trans,
    float* __restrict__ out) {
    __shared__ float fv[2][NTAGS];
    __shared__ unsigned char bp[SEQ * NTAGS];  // 24 KB
    __shared__ float featbuf[256 * NTAGS];     // 12 KB
    __shared__ float term[NTAGS];
    int lane = threadIdx.x;

    float tr[NTAGS];
    if (lane < NTAGS) {
#pragma unroll
        for (int p = 0; p < NTAGS; ++p) tr[p] = trans[lane * NTAGS + p];
        fv[0][lane] = (lane == START_TAG) ? 0.f : NEGV;
    }
    __syncthreads();

    int cur = 0;
    for (int tc = 0; tc < SEQ; tc += 256) {
        for (int i = lane; i < 256 * NTAGS; i += 64) featbuf[i] = feats[tc * NTAGS + i];
        __syncthreads();
        for (int tt = 0; tt < 256; ++tt) {
            int t = tc + tt;
            if (lane < NTAGS) {
                float best = fv[cur][0] + tr[0];
                int bi = 0;
#pragma unroll
                for (int p = 1; p < NTAGS; ++p) {
                    float s = fv[cur][p] + tr[p];
                    if (s > best) { best = s; bi = p; }  // strict > keeps first max (jnp.argmax)
                }
                bp[t * NTAGS + lane] = (unsigned char)bi;
                fv[cur ^ 1][lane] = best + featbuf[tt * NTAGS + lane];
            }
            cur ^= 1;
            __syncthreads();
        }
    }

    if (lane < NTAGS) term[lane] = fv[cur][lane] + trans[STOP_TAG * NTAGS + lane];
    __syncthreads();
    if (lane == 0) {
        float best = term[0];
        int bi = 0;
        for (int p = 1; p < NTAGS; ++p) {
            if (term[p] > best) { best = term[p]; bi = p; }
        }
        out[0] = best;
        int tag = bi;
        out[1 + (SEQ - 1)] = (float)tag;
        for (int t = SEQ - 1; t >= 1; --t) {
            tag = bp[t * NTAGS + tag];
            out[t] = (float)tag;  // out[1+(t-1)]
        }
    }
}

// ---------------------------------------------------------------------------
extern "C" void kernel_launch(void* const* d_in, const int* in_sizes, int n_in,
                              void* d_out, int out_size, void* d_ws, size_t ws_size,
                              hipStream_t stream) {
    const int* sent = (const int*)d_in[0];
    const float* emb = (const float*)d_in[1];
    const float* Wih0 = (const float*)d_in[2];
    const float* Whh0 = (const float*)d_in[3];
    const float* bih0 = (const float*)d_in[4];
    const float* bhh0 = (const float*)d_in[5];
    const float* Wih1 = (const float*)d_in[6];
    const float* Whh1 = (const float*)d_in[7];
    const float* bih1 = (const float*)d_in[8];
    const float* bhh1 = (const float*)d_in[9];
    const float* Wtag = (const float*)d_in[10];
    const float* btag = (const float*)d_in[11];
    const float* trans = (const float*)d_in[12];
    float* out = (float*)d_out;

    char* ws = (char*)d_ws;
    size_t off = 0;
    auto alloc = [&](size_t bytes) {
        void* p = ws + off;
        off += (bytes + 255) & ~(size_t)255;
        return p;
    };
    float* x0 = (float*)alloc(2048ull * 512 * 4);          // 4 MB
    float* Gi = (float*)alloc(2ull * 2048 * 2048 * 4);     // 32 MB (reused layer0/1)
    float* h0 = (float*)alloc(2ull * 2048 * 512 * 4);      // 8 MB
    float* h1 = (float*)alloc(2ull * 2048 * 512 * 4);      // 8 MB
    float* feats = (float*)alloc(2048ull * NTAGS * 4);

    // poison h buffers: "not yet written" sentinel for the data-polling sync
    hipMemsetAsync(h0, 0xAA, 2ull * 2048 * 512 * 4, stream);
    hipMemsetAsync(h1, 0xAA, 2ull * 2048 * 512 * 4, stream);

    k_embed<<<2048, 128, 0, stream>>>(sent, emb, x0);

    dim3 gg(32, 32, 2);
    // layer 0 input gates: Gi = x0 @ Wih0^T + bih0 + bhh0  (K=512)
    k_gemm<<<gg, 256, 0, stream>>>(x0, x0, Wih0, bih0, bhh0, Gi, 512);
    // layer 0 recurrence
    k_lstm<<<256, 256, 0, stream>>>(Whh0, Gi, h0);
    // layer 1 input gates: Gi = concat(h0f,h0b) @ Wih1^T + b  (K=1024)
    k_gemm<<<gg, 256, 0, stream>>>(h0, h0 + 2048ull * 512, Wih1, bih1, bhh1, Gi, 1024);
    // layer 1 recurrence
    k_lstm<<<256, 256, 0, stream>>>(Whh1, Gi, h1);
    // tag projection
    k_feats<<<2048, 64, 0, stream>>>(h1, Wtag, btag, feats);
    // viterbi decode
    k_viterbi<<<1, 64, 0, stream>>>(feats, trans, out);
}

// Round 5
// 15861.687 us; speedup vs baseline: 1.3962x; 1.3962x over previous
//
#include <hip/hip_runtime.h>
#include <math.h>

// Problem constants
#define SEQ 2048
#define EMB_D 512
#define HID 512
#define NTAGS 12
#define START_TAG 10
#define STOP_TAG 11
#define NEGV (-10000.0f)
#define POISON 0xAAAAAAAAu

// fast transcendentals (v_exp_f32 + v_rcp_f32); saturate correctly at +-inf
__device__ __forceinline__ float sigf(float x) {
    return __fdividef(1.f, 1.f + __expf(-x));
}
__device__ __forceinline__ float tanh_fast(float x) {
    return 1.f - __fdividef(2.f, __expf(2.f * x) + 1.f);
}

__device__ __forceinline__ bool is_poison(float x) {
    return __float_as_uint(x) == POISON;
}

// ---------------------------------------------------------------------------
// K0: embedding gather  x0[t][e] = emb[sentence[t]][e]
// ---------------------------------------------------------------------------
__global__ void k_embed(const int* __restrict__ sent, const float* __restrict__ emb,
                        float* __restrict__ x0) {
    int t = blockIdx.x;
    int tid = threadIdx.x;  // 128 threads, 128 float4 = 512 floats
    int row = sent[t];
    const float4* src = (const float4*)(emb + (size_t)row * EMB_D);
    float4* dst = (float4*)(x0 + (size_t)t * EMB_D);
    dst[tid] = src[tid];
}

// ---------------------------------------------------------------------------
// K1/K3: fp32 GEMM  C[d][m][n] = sum_k A[m][k] * B[d][n][k] + biasA[d][n]+biasB[d][n]
// A[m][k] = (k<512 ? Af[m*512+k] : Ab[m*512+(k-512)])  (handles concat input)
// M = N = 2048 fixed, K in {512,1024}. Tile 64x64, BK=32, 256 threads, 4x4/thread.
// ---------------------------------------------------------------------------
#define BM 64
#define BN 64
#define BKT 32
#define LDT 68

__global__ __launch_bounds__(256) void k_gemm(
    const float* __restrict__ Af, const float* __restrict__ Ab,
    const float* __restrict__ B,
    const float* __restrict__ biasA, const float* __restrict__ biasB,
    float* __restrict__ C, int K) {
    const int N = 2048;
    int dir = blockIdx.z;
    const float* Bd = B + (size_t)dir * N * K;
    const float* bA = biasA + dir * N;
    const float* bB = biasB + dir * N;
    float* Cd = C + (size_t)dir * 2048 * N;
    int m0 = blockIdx.y * BM, n0 = blockIdx.x * BN;

    __shared__ float As[BKT * LDT];
    __shared__ float Bs[BKT * LDT];

    int tid = threadIdx.x;
    int lrow = tid >> 2;          // 0..63
    int lk4 = (tid & 3) * 8;      // 0,8,16,24
    int tx = tid & 15, ty = tid >> 4;

    float acc[4][4] = {};

    for (int kt = 0; kt < K; kt += BKT) {
        // load A tile (k-major in LDS)
        {
            int m = m0 + lrow;
#pragma unroll
            for (int hh = 0; hh < 2; ++hh) {
                int k = kt + lk4 + hh * 4;
                const float* src = (k < 512) ? (Af + (size_t)m * 512 + k)
                                             : (Ab + (size_t)m * 512 + (k - 512));
                float4 v = *(const float4*)src;
                int kl = lk4 + hh * 4;
                As[(kl + 0) * LDT + lrow] = v.x;
                As[(kl + 1) * LDT + lrow] = v.y;
                As[(kl + 2) * LDT + lrow] = v.z;
                As[(kl + 3) * LDT + lrow] = v.w;
            }
        }
        // load B tile
        {
            int n = n0 + lrow;
#pragma unroll
            for (int hh = 0; hh < 2; ++hh) {
                int k = kt + lk4 + hh * 4;
                float4 v = *(const float4*)(Bd + (size_t)n * K + k);
                int kl = lk4 + hh * 4;
                Bs[(kl + 0) * LDT + lrow] = v.x;
                Bs[(kl + 1) * LDT + lrow] = v.y;
                Bs[(kl + 2) * LDT + lrow] = v.z;
                Bs[(kl + 3) * LDT + lrow] = v.w;
            }
        }
        __syncthreads();
#pragma unroll
        for (int kk = 0; kk < BKT; ++kk) {
            float4 av = *(const float4*)&As[kk * LDT + ty * 4];
            float4 bv = *(const float4*)&Bs[kk * LDT + tx * 4];
            acc[0][0] += av.x * bv.x; acc[0][1] += av.x * bv.y; acc[0][2] += av.x * bv.z; acc[0][3] += av.x * bv.w;
            acc[1][0] += av.y * bv.x; acc[1][1] += av.y * bv.y; acc[1][2] += av.y * bv.z; acc[1][3] += av.y * bv.w;
            acc[2][0] += av.z * bv.x; acc[2][1] += av.z * bv.y; acc[2][2] += av.z * bv.z; acc[2][3] += av.z * bv.w;
            acc[3][0] += av.w * bv.x; acc[3][1] += av.w * bv.y; acc[3][2] += av.w * bv.z; acc[3][3] += av.w * bv.w;
        }
        __syncthreads();
    }
#pragma unroll
    for (int i = 0; i < 4; ++i) {
        int m = m0 + ty * 4 + i;
#pragma unroll
        for (int j = 0; j < 4; ++j) {
            int n = n0 + tx * 4 + j;
            Cd[(size_t)m * N + n] = acc[i][j] + bA[n] + bB[n];
        }
    }
}

// ---------------------------------------------------------------------------
// K2/K4: LSTM recurrence, one layer, both directions.
// 256 WGs (128/dir, 1 per CU), 256 threads each, persistent over 2048 steps.
// Each WG owns 4 hidden units; one wave = one unit. Weights live in LDS
// (32 KB/WG, staged once — LDS reads cannot be rematerialized into global
// re-loads, unlike the register-array attempts of R2-R4 which all sank).
// LDS layout is lane-major float4 pairs so per-step weight reads are 8
// conflict-free ds_read_b128 per lane.
// Sync (proven in R2/R3): producers publish h with relaxed agent-scope
// stores (coherent at LLC); consumers poll the data words themselves
// (0xAA poison = "not yet written"). One __syncthreads per step,
// double-buffered hlds.
// ---------------------------------------------------------------------------
__global__ __launch_bounds__(256, 1) void k_lstm(
    const float* __restrict__ Whh,  // [2][2048][512]
    const float* __restrict__ Gi,   // [2][2048][2048]  (Wih@x + bih + bhh)
    float* __restrict__ hstore)     // [2][2048][512], pre-poisoned 0xAA
{
    int wg = blockIdx.x;            // 0..255
    int dir = wg >> 7;              // 0 fwd, 1 bwd
    int tid = threadIdx.x;
    int wave = tid >> 6;            // 0..3 — unit index within WG
    int q = tid & 63;               // lane: 8-wide k-slice owner
    int u = (wg & 127) * 4 + wave;  // hidden unit 0..511

    const float* Whh_d = Whh + (size_t)dir * 2048 * 512;
    const float* Gi_d = Gi + (size_t)dir * 2048 * 2048;
    float* h_d = hstore + (size_t)dir * 2048 * 512;

    // LDS weights: row r = wave*4+gate (16 rows). Two float4 banks per row,
    // lane-major: wlds[(r*2+half)*64 + q] = Whh[g*512+u][q*8 + half*4 ...]
    __shared__ __align__(16) float4 wlds[16 * 2 * 64];  // 32 KB
    __shared__ __align__(16) float hlds[2][512];        // 4 KB

#pragma unroll
    for (int g = 0; g < 4; ++g) {
        const float4* ws = (const float4*)(Whh_d + (size_t)(g * 512 + u) * 512 + q * 8);
        wlds[((wave * 4 + g) * 2 + 0) * 64 + q] = ws[0];
        wlds[((wave * 4 + g) * 2 + 1) * 64 + q] = ws[1];
    }
    __syncthreads();

    float c_reg = 0.0f;

    for (int it = 0; it < 2048; ++it) {
        int t = dir ? (2047 - it) : it;
        int b = it & 1;

        // Gi prefetch (lanes 0..3 pick up gate q's input term) — before poll
        float gi = 0.f;
        if (q < 4) gi = Gi_d[(size_t)t * 2048 + q * 512 + u];

        if (it == 0) {
            ((float2*)hlds[0])[tid] = make_float2(0.f, 0.f);
        } else {
            int tprev = dir ? (t + 1) : (t - 1);
            const float* src = h_d + (size_t)tprev * 512 + 2 * tid;
            float a, bb;
            do {
                a = __hip_atomic_load(src + 0, __ATOMIC_RELAXED, __HIP_MEMORY_SCOPE_AGENT);
                bb = __hip_atomic_load(src + 1, __ATOMIC_RELAXED, __HIP_MEMORY_SCOPE_AGENT);
            } while (is_poison(a) || is_poison(bb));
            hlds[b][2 * tid] = a;
            hlds[b][2 * tid + 1] = bb;
        }
        __syncthreads();

        // this lane's 8-wide h slice
        float4 ha = ((const float4*)hlds[b])[q * 2 + 0];
        float4 hb = ((const float4*)hlds[b])[q * 2 + 1];

        // 4 gate partial dots, weights streamed from LDS (8x ds_read_b128)
        float acc0, acc1, acc2, acc3;
        {
            float4 w0 = wlds[((wave * 4 + 0) * 2 + 0) * 64 + q];
            float4 w1 = wlds[((wave * 4 + 0) * 2 + 1) * 64 + q];
            acc0 = w0.x * ha.x + w0.y * ha.y + w0.z * ha.z + w0.w * ha.w
                 + w1.x * hb.x + w1.y * hb.y + w1.z * hb.z + w1.w * hb.w;
        }
        {
            float4 w0 = wlds[((wave * 4 + 1) * 2 + 0) * 64 + q];
            float4 w1 = wlds[((wave * 4 + 1) * 2 + 1) * 64 + q];
            acc1 = w0.x * ha.x + w0.y * ha.y + w0.z * ha.z + w0.w * ha.w
                 + w1.x * hb.x + w1.y * hb.y + w1.z * hb.z + w1.w * hb.w;
        }
        {
            float4 w0 = wlds[((wave * 4 + 2) * 2 + 0) * 64 + q];
            float4 w1 = wlds[((wave * 4 + 2) * 2 + 1) * 64 + q];
            acc2 = w0.x * ha.x + w0.y * ha.y + w0.z * ha.z + w0.w * ha.w
                 + w1.x * hb.x + w1.y * hb.y + w1.z * hb.z + w1.w * hb.w;
        }
        {
            float4 w0 = wlds[((wave * 4 + 3) * 2 + 0) * 64 + q];
            float4 w1 = wlds[((wave * 4 + 3) * 2 + 1) * 64 + q];
            acc3 = w0.x * ha.x + w0.y * ha.y + w0.z * ha.z + w0.w * ha.w
                 + w1.x * hb.x + w1.y * hb.y + w1.z * hb.z + w1.w * hb.w;
        }
        // fold the precomputed input terms in before the reduce
        acc0 += (q == 0) ? gi : 0.f;
        acc1 += (q == 1) ? gi : 0.f;
        acc2 += (q == 2) ? gi : 0.f;
        acc3 += (q == 3) ? gi : 0.f;
        // butterfly reduce across the wave (all lanes end with the totals)
#pragma unroll
        for (int m = 1; m < 64; m <<= 1) {
            acc0 += __shfl_xor(acc0, m);
            acc1 += __shfl_xor(acc1, m);
            acc2 += __shfl_xor(acc2, m);
            acc3 += __shfl_xor(acc3, m);
        }

        // torch gate order: i,f,g,o = acc0,acc1,acc2,acc3 (uniform on all lanes)
        float c = sigf(acc1) * c_reg + sigf(acc0) * tanh_fast(acc2);
        float h = sigf(acc3) * tanh_fast(c);
        c_reg = c;
        if (q == 0) {
            // publish at the coherent point; the value itself is the flag
            __hip_atomic_store(h_d + (size_t)t * 512 + u, h,
                               __ATOMIC_RELAXED, __HIP_MEMORY_SCOPE_AGENT);
        }
    }
}

// ---------------------------------------------------------------------------
// K5: feats[t][tag] = sum_k concat(h1f[t],h1b[t])[k] * W_tag[tag][k] + b_tag[tag]
// one 64-thread block per t
// ---------------------------------------------------------------------------
__global__ __launch_bounds__(64) void k_feats(
    const float* __restrict__ h1,  // [2][2048][512]
    const float* __restrict__ Wt,  // [12][1024]
    const float* __restrict__ bt,  // [12]
    float* __restrict__ feats)     // [2048][12]
{
    int t = blockIdx.x;
    int lane = threadIdx.x;
    __shared__ __align__(16) float xl[1024];
    const float4* hf = (const float4*)(h1 + (size_t)t * 512);
    const float4* hb = (const float4*)(h1 + (size_t)(2048 + t) * 512);
    ((float4*)xl)[lane] = hf[lane];
    ((float4*)xl)[lane + 64] = hf[lane + 64];
    ((float4*)xl)[128 + lane] = hb[lane];
    ((float4*)xl)[128 + lane + 64] = hb[lane + 64];
    __syncthreads();
    for (int tag = 0; tag < NTAGS; ++tag) {
        const float* wrow = Wt + tag * 1024;
        float s = 0.f;
        for (int k = lane; k < 1024; k += 64) s += xl[k] * wrow[k];
#pragma unroll
        for (int off = 32; off; off >>= 1) s += __shfl_xor(s, off);
        if (lane == 0) feats[t * NTAGS + tag] = s + bt[tag];
    }
}

// ---------------------------------------------------------------------------
// K6: Viterbi forward + backtrack, single 64-thread block.
// Backpointers kept in LDS as uchar; feats prefetched in 256-step chunks.
// out[0] = path_score, out[1..2048] = best_path (as floats)
// ---------------------------------------------------------------------------
__global__ __launch_bounds__(64) void k_viterbi(
    const float* __restrict__ feats, const float* __restrict__ trans,
    float* __restrict__ out) {
    __shared__ float fv[2][NTAGS];
    __shared__ unsigned char bp[SEQ * NTAGS];  // 24 KB
    __shared__ float featbuf[256 * NTAGS];     // 12 KB
    __shared__ float term[NTAGS];
    int lane = threadIdx.x;

    float tr[NTAGS];
    if (lane < NTAGS) {
#pragma unroll
        for (int p = 0; p < NTAGS; ++p) tr[p] = trans[lane * NTAGS + p];
        fv[0][lane] = (lane == START_TAG) ? 0.f : NEGV;
    }
    __syncthreads();

    int cur = 0;
    for (int tc = 0; tc < SEQ; tc += 256) {
        for (int i = lane; i < 256 * NTAGS; i += 64) featbuf[i] = feats[tc * NTAGS + i];
        __syncthreads();
        for (int tt = 0; tt < 256; ++tt) {
            int t = tc + tt;
            if (lane < NTAGS) {
                float best = fv[cur][0] + tr[0];
                int bi = 0;
#pragma unroll
                for (int p = 1; p < NTAGS; ++p) {
                    float s = fv[cur][p] + tr[p];
                    if (s > best) { best = s; bi = p; }  // strict > keeps first max (jnp.argmax)
                }
                bp[t * NTAGS + lane] = (unsigned char)bi;
                fv[cur ^ 1][lane] = best + featbuf[tt * NTAGS + lane];
            }
            cur ^= 1;
            __syncthreads();
        }
    }

    if (lane < NTAGS) term[lane] = fv[cur][lane] + trans[STOP_TAG * NTAGS + lane];
    __syncthreads();
    if (lane == 0) {
        float best = term[0];
        int bi = 0;
        for (int p = 1; p < NTAGS; ++p) {
            if (term[p] > best) { best = term[p]; bi = p; }
        }
        out[0] = best;
        int tag = bi;
        out[1 + (SEQ - 1)] = (float)tag;
        for (int t = SEQ - 1; t >= 1; --t) {
            tag = bp[t * NTAGS + tag];
            out[t] = (float)tag;  // out[1+(t-1)]
        }
    }
}

// ---------------------------------------------------------------------------
extern "C" void kernel_launch(void* const* d_in, const int* in_sizes, int n_in,
                              void* d_out, int out_size, void* d_ws, size_t ws_size,
                              hipStream_t stream) {
    const int* sent = (const int*)d_in[0];
    const float* emb = (const float*)d_in[1];
    const float* Wih0 = (const float*)d_in[2];
    const float* Whh0 = (const float*)d_in[3];
    const float* bih0 = (const float*)d_in[4];
    const float* bhh0 = (const float*)d_in[5];
    const float* Wih1 = (const float*)d_in[6];
    const float* Whh1 = (const float*)d_in[7];
    const float* bih1 = (const float*)d_in[8];
    const float* bhh1 = (const float*)d_in[9];
    const float* Wtag = (const float*)d_in[10];
    const float* btag = (const float*)d_in[11];
    const float* trans = (const float*)d_in[12];
    float* out = (float*)d_out;

    char* ws = (char*)d_ws;
    size_t off = 0;
    auto alloc = [&](size_t bytes) {
        void* p = ws + off;
        off += (bytes + 255) & ~(size_t)255;
        return p;
    };
    float* x0 = (float*)alloc(2048ull * 512 * 4);          // 4 MB
    float* Gi = (float*)alloc(2ull * 2048 * 2048 * 4);     // 32 MB (reused layer0/1)
    float* h0 = (float*)alloc(2ull * 2048 * 512 * 4);      // 8 MB
    float* h1 = (float*)alloc(2ull * 2048 * 512 * 4);      // 8 MB
    float* feats = (float*)alloc(2048ull * NTAGS * 4);

    // poison h buffers: "not yet written" sentinel for the data-polling sync
    hipMemsetAsync(h0, 0xAA, 2ull * 2048 * 512 * 4, stream);
    hipMemsetAsync(h1, 0xAA, 2ull * 2048 * 512 * 4, stream);

    k_embed<<<2048, 128, 0, stream>>>(sent, emb, x0);

    dim3 gg(32, 32, 2);
    // layer 0 input gates: Gi = x0 @ Wih0^T + bih0 + bhh0  (K=512)
    k_gemm<<<gg, 256, 0, stream>>>(x0, x0, Wih0, bih0, bhh0, Gi, 512);
    // layer 0 recurrence
    k_lstm<<<256, 256, 0, stream>>>(Whh0, Gi, h0);
    // layer 1 input gates: Gi = concat(h0f,h0b) @ Wih1^T + b  (K=1024)
    k_gemm<<<gg, 256, 0, stream>>>(h0, h0 + 2048ull * 512, Wih1, bih1, bhh1, Gi, 1024);
    // layer 1 recurrence
    k_lstm<<<256, 256, 0, stream>>>(Whh1, Gi, h1);
    // tag projection
    k_feats<<<2048, 64, 0, stream>>>(h1, Wtag, btag, feats);
    // viterbi decode
    k_viterbi<<<1, 64, 0, stream>>>(feats, trans, out);
}

// Round 6
// 10791.399 us; speedup vs baseline: 2.0522x; 1.4698x over previous
//
#include <hip/hip_runtime.h>
#include <math.h>

// Problem constants
#define SEQ 2048
#define EMB_D 512
#define HID 512
#define NTAGS 12
#define START_TAG 10
#define STOP_TAG 11
#define NEGV (-10000.0f)
#define POISON 0xAAAAAAAAu

// fast transcendentals (v_exp_f32 + v_rcp_f32); saturate correctly at +-inf
__device__ __forceinline__ float sigf(float x) {
    return __fdividef(1.f, 1.f + __expf(-x));
}
__device__ __forceinline__ float tanh_fast(float x) {
    return 1.f - __fdividef(2.f, __expf(2.f * x) + 1.f);
}

__device__ __forceinline__ bool is_poison(float x) {
    return __float_as_uint(x) == POISON;
}

// ---------------------------------------------------------------------------
// K0: embedding gather  x0[t][e] = emb[sentence[t]][e]
// ---------------------------------------------------------------------------
__global__ void k_embed(const int* __restrict__ sent, const float* __restrict__ emb,
                        float* __restrict__ x0) {
    int t = blockIdx.x;
    int tid = threadIdx.x;  // 128 threads, 128 float4 = 512 floats
    int row = sent[t];
    const float4* src = (const float4*)(emb + (size_t)row * EMB_D);
    float4* dst = (float4*)(x0 + (size_t)t * EMB_D);
    dst[tid] = src[tid];
}

// ---------------------------------------------------------------------------
// K1/K3: fp32 GEMM  C[d][m][n] = sum_k A[m][k] * B[d][n][k] + biasA[d][n]+biasB[d][n]
// A[m][k] = (k<512 ? Af[m*512+k] : Ab[m*512+(k-512)])  (handles concat input)
// M = N = 2048 fixed, K in {512,1024}. Tile 64x64, BK=32, 256 threads, 4x4/thread.
// ---------------------------------------------------------------------------
#define BM 64
#define BN 64
#define BKT 32
#define LDT 68

__global__ __launch_bounds__(256) void k_gemm(
    const float* __restrict__ Af, const float* __restrict__ Ab,
    const float* __restrict__ B,
    const float* __restrict__ biasA, const float* __restrict__ biasB,
    float* __restrict__ C, int K) {
    const int N = 2048;
    int dir = blockIdx.z;
    const float* Bd = B + (size_t)dir * N * K;
    const float* bA = biasA + dir * N;
    const float* bB = biasB + dir * N;
    float* Cd = C + (size_t)dir * 2048 * N;
    int m0 = blockIdx.y * BM, n0 = blockIdx.x * BN;

    __shared__ float As[BKT * LDT];
    __shared__ float Bs[BKT * LDT];

    int tid = threadIdx.x;
    int lrow = tid >> 2;          // 0..63
    int lk4 = (tid & 3) * 8;      // 0,8,16,24
    int tx = tid & 15, ty = tid >> 4;

    float acc[4][4] = {};

    for (int kt = 0; kt < K; kt += BKT) {
        // load A tile (k-major in LDS)
        {
            int m = m0 + lrow;
#pragma unroll
            for (int hh = 0; hh < 2; ++hh) {
                int k = kt + lk4 + hh * 4;
                const float* src = (k < 512) ? (Af + (size_t)m * 512 + k)
                                             : (Ab + (size_t)m * 512 + (k - 512));
                float4 v = *(const float4*)src;
                int kl = lk4 + hh * 4;
                As[(kl + 0) * LDT + lrow] = v.x;
                As[(kl + 1) * LDT + lrow] = v.y;
                As[(kl + 2) * LDT + lrow] = v.z;
                As[(kl + 3) * LDT + lrow] = v.w;
            }
        }
        // load B tile
        {
            int n = n0 + lrow;
#pragma unroll
            for (int hh = 0; hh < 2; ++hh) {
                int k = kt + lk4 + hh * 4;
                float4 v = *(const float4*)(Bd + (size_t)n * K + k);
                int kl = lk4 + hh * 4;
                Bs[(kl + 0) * LDT + lrow] = v.x;
                Bs[(kl + 1) * LDT + lrow] = v.y;
                Bs[(kl + 2) * LDT + lrow] = v.z;
                Bs[(kl + 3) * LDT + lrow] = v.w;
            }
        }
        __syncthreads();
#pragma unroll
        for (int kk = 0; kk < BKT; ++kk) {
            float4 av = *(const float4*)&As[kk * LDT + ty * 4];
            float4 bv = *(const float4*)&Bs[kk * LDT + tx * 4];
            acc[0][0] += av.x * bv.x; acc[0][1] += av.x * bv.y; acc[0][2] += av.x * bv.z; acc[0][3] += av.x * bv.w;
            acc[1][0] += av.y * bv.x; acc[1][1] += av.y * bv.y; acc[1][2] += av.y * bv.z; acc[1][3] += av.y * bv.w;
            acc[2][0] += av.z * bv.x; acc[2][1] += av.z * bv.y; acc[2][2] += av.z * bv.z; acc[2][3] += av.z * bv.w;
            acc[3][0] += av.w * bv.x; acc[3][1] += av.w * bv.y; acc[3][2] += av.w * bv.z; acc[3][3] += av.w * bv.w;
        }
        __syncthreads();
    }
#pragma unroll
    for (int i = 0; i < 4; ++i) {
        int m = m0 + ty * 4 + i;
#pragma unroll
        for (int j = 0; j < 4; ++j) {
            int n = n0 + tx * 4 + j;
            Cd[(size_t)m * N + n] = acc[i][j] + bA[n] + bB[n];
        }
    }
}

// ---------------------------------------------------------------------------
// K2/K4: LSTM recurrence, one layer, both directions.
// 64 WGs (32 per direction — R2's proven low-contention poll topology),
// 256 threads each, persistent over 2048 steps. Each WG owns 16 hidden
// units -> 64 gate rows x 512 weights = 128 KB, LDS-RESIDENT (fits the
// 160 KB CU budget; this is why 64 WGs is the magic number). Weights are
// stored in CONSUMPTION ORDER: wlds4[(wave*32+g*8+jj)*64 + lane], so each
// per-step weight read is a wave-contiguous ds_read_b128 (lane i at
// base+16*i) -> conflict-free by construction.
// One wave = 4 units; 16 lanes per unit; lane q owns an interleaved
// 32-float slice (float4 chunks q+16*jj) of all 4 gate rows. Butterfly
// reduce over the 16-lane group; gi folded pre-reduce; lane q==0 publishes.
// Sync (proven R2): relaxed agent-scope store of h (coherent at LLC);
// consumers poll the data words (0xAA poison = "not yet written").
// One __syncthreads per step, double-buffered hlds.
// ---------------------------------------------------------------------------
__global__ __launch_bounds__(256, 1) void k_lstm(
    const float* __restrict__ Whh,  // [2][2048][512]
    const float* __restrict__ Gi,   // [2][2048][2048]  (Wih@x + bih + bhh)
    float* __restrict__ hstore)     // [2][2048][512], pre-poisoned 0xAA
{
    int wg = blockIdx.x;            // 0..63
    int dir = wg >> 5;              // 0 fwd, 1 bwd
    int slice = wg & 31;
    int u_base = slice * 16;
    int tid = threadIdx.x;
    int wave = tid >> 6;            // 0..3
    int lane = tid & 63;
    int uu = (tid >> 4) & 3;        // unit-in-wave 0..3
    int q = tid & 15;               // 16-lane slot within unit
    int u = u_base + wave * 4 + uu; // this lane's hidden unit

    const float* Whh_d = Whh + (size_t)dir * 2048 * 512;
    const float* Gi_d = Gi + (size_t)dir * 2048 * 2048;
    float* h_d = hstore + (size_t)dir * 2048 * 512;

    // 128 KB weights + 4 KB h double-buffer = 132 KB LDS
    __shared__ __align__(16) float4 wlds4[8192];   // [wave][g*8+jj][lane]
    __shared__ __align__(16) float hlds[2][512];

    // stage weights once, in consumption order:
    // wlds4[(wave*32 + g*8 + jj)*64 + lane] = Whh[g*512+u][ (q+16*jj)*4 .. +3 ]
#pragma unroll
    for (int g = 0; g < 4; ++g) {
        const float4* wsrc = (const float4*)(Whh_d + (size_t)(g * 512 + u) * 512);
#pragma unroll
        for (int jj = 0; jj < 8; ++jj) {
            wlds4[(wave * 32 + g * 8 + jj) * 64 + lane] = wsrc[q + 16 * jj];
        }
    }
    __syncthreads();

    float c_reg = 0.0f;

    for (int it = 0; it < 2048; ++it) {
        int t = dir ? (2047 - it) : it;
        int b = it & 1;

        // Gi prefetch (lanes q<4 pick up gate q's input term) — before poll
        float gi = 0.f;
        if (q < 4) gi = Gi_d[(size_t)t * 2048 + q * 512 + u];

        if (it == 0) {
            ((float2*)hlds[0])[tid] = make_float2(0.f, 0.f);
        } else {
            int tprev = dir ? (t + 1) : (t - 1);
            const float* src = h_d + (size_t)tprev * 512 + 2 * tid;
            float a, bb;
            do {
                a = __hip_atomic_load(src + 0, __ATOMIC_RELAXED, __HIP_MEMORY_SCOPE_AGENT);
                bb = __hip_atomic_load(src + 1, __ATOMIC_RELAXED, __HIP_MEMORY_SCOPE_AGENT);
            } while (is_poison(a) || is_poison(bb));
            hlds[b][2 * tid] = a;
            hlds[b][2 * tid + 1] = bb;
        }
        __syncthreads();

        // this lane's interleaved 32-float h slice (chunks q+16*jj);
        // 16 distinct addrs/instr, 2-way banks -> free; reused across 4 gates
        float4 hv[8];
        {
            const float4* h4 = (const float4*)hlds[b];
#pragma unroll
            for (int jj = 0; jj < 8; ++jj) hv[jj] = h4[q + 16 * jj];
        }

        // 4 gate partial dots; weight reads are wave-contiguous b128
        float acc0 = 0.f, acc1 = 0.f, acc2 = 0.f, acc3 = 0.f;
        {
            const float4* wbase = &wlds4[(size_t)wave * 32 * 64 + lane];
#pragma unroll
            for (int jj = 0; jj < 8; ++jj) {
                float4 w = wbase[(0 * 8 + jj) * 64];
                acc0 += w.x * hv[jj].x + w.y * hv[jj].y + w.z * hv[jj].z + w.w * hv[jj].w;
            }
#pragma unroll
            for (int jj = 0; jj < 8; ++jj) {
                float4 w = wbase[(1 * 8 + jj) * 64];
                acc1 += w.x * hv[jj].x + w.y * hv[jj].y + w.z * hv[jj].z + w.w * hv[jj].w;
            }
#pragma unroll
            for (int jj = 0; jj < 8; ++jj) {
                float4 w = wbase[(2 * 8 + jj) * 64];
                acc2 += w.x * hv[jj].x + w.y * hv[jj].y + w.z * hv[jj].z + w.w * hv[jj].w;
            }
#pragma unroll
            for (int jj = 0; jj < 8; ++jj) {
                float4 w = wbase[(3 * 8 + jj) * 64];
                acc3 += w.x * hv[jj].x + w.y * hv[jj].y + w.z * hv[jj].z + w.w * hv[jj].w;
            }
        }
        // fold the precomputed input terms in before the reduce
        acc0 += (q == 0) ? gi : 0.f;
        acc1 += (q == 1) ? gi : 0.f;
        acc2 += (q == 2) ? gi : 0.f;
        acc3 += (q == 3) ? gi : 0.f;
        // butterfly reduce across the 16-lane unit group
#pragma unroll
        for (int m = 1; m < 16; m <<= 1) {
            acc0 += __shfl_xor(acc0, m);
            acc1 += __shfl_xor(acc1, m);
            acc2 += __shfl_xor(acc2, m);
            acc3 += __shfl_xor(acc3, m);
        }

        // torch gate order: i,f,g,o = acc0..acc3 (uniform within 16-group)
        float c = sigf(acc1) * c_reg + sigf(acc0) * tanh_fast(acc2);
        float h = sigf(acc3) * tanh_fast(c);
        c_reg = c;
        if (q == 0) {
            // publish at the coherent point; the value itself is the flag
            __hip_atomic_store(h_d + (size_t)t * 512 + u, h,
                               __ATOMIC_RELAXED, __HIP_MEMORY_SCOPE_AGENT);
        }
    }
}

// ---------------------------------------------------------------------------
// K5: feats[t][tag] = sum_k concat(h1f[t],h1b[t])[k] * W_tag[tag][k] + b_tag[tag]
// one 64-thread block per t
// ---------------------------------------------------------------------------
__global__ __launch_bounds__(64) void k_feats(
    const float* __restrict__ h1,  // [2][2048][512]
    const float* __restrict__ Wt,  // [12][1024]
    const float* __restrict__ bt,  // [12]
    float* __restrict__ feats)     // [2048][12]
{
    int t = blockIdx.x;
    int lane = threadIdx.x;
    __shared__ __align__(16) float xl[1024];
    const float4* hf = (const float4*)(h1 + (size_t)t * 512);
    const float4* hb = (const float4*)(h1 + (size_t)(2048 + t) * 512);
    ((float4*)xl)[lane] = hf[lane];
    ((float4*)xl)[lane + 64] = hf[lane + 64];
    ((float4*)xl)[128 + lane] = hb[lane];
    ((float4*)xl)[128 + lane + 64] = hb[lane + 64];
    __syncthreads();
    for (int tag = 0; tag < NTAGS; ++tag) {
        const float* wrow = Wt + tag * 1024;
        float s = 0.f;
        for (int k = lane; k < 1024; k += 64) s += xl[k] * wrow[k];
#pragma unroll
        for (int off = 32; off; off >>= 1) s += __shfl_xor(s, off);
        if (lane == 0) feats[t * NTAGS + tag] = s + bt[tag];
    }
}

// ---------------------------------------------------------------------------
// K6: Viterbi forward + backtrack, single 64-thread block.
// Backpointers kept in LDS as uchar; feats prefetched in 256-step chunks.
// out[0] = path_score, out[1..2048] = best_path (as floats)
// ---------------------------------------------------------------------------
__global__ __launch_bounds__(64) void k_viterbi(
    const float* __restrict__ feats, const float* __restrict__ trans,
    float* __restrict__ out) {
    __shared__ float fv[2][NTAGS];
    __shared__ unsigned char bp[SEQ * NTAGS];  // 24 KB
    __shared__ float featbuf[256 * NTAGS];     // 12 KB
    __shared__ float term[NTAGS];
    int lane = threadIdx.x;

    float tr[NTAGS];
    if (lane < NTAGS) {
#pragma unroll
        for (int p = 0; p < NTAGS; ++p) tr[p] = trans[lane * NTAGS + p];
        fv[0][lane] = (lane == START_TAG) ? 0.f : NEGV;
    }
    __syncthreads();

    int cur = 0;
    for (int tc = 0; tc < SEQ; tc += 256) {
        for (int i = lane; i < 256 * NTAGS; i += 64) featbuf[i] = feats[tc * NTAGS + i];
        __syncthreads();
        for (int tt = 0; tt < 256; ++tt) {
            int t = tc + tt;
            if (lane < NTAGS) {
                float best = fv[cur][0] + tr[0];
                int bi = 0;
#pragma unroll
                for (int p = 1; p < NTAGS; ++p) {
                    float s = fv[cur][p] + tr[p];
                    if (s > best) { best = s; bi = p; }  // strict > keeps first max (jnp.argmax)
                }
                bp[t * NTAGS + lane] = (unsigned char)bi;
                fv[cur ^ 1][lane] = best + featbuf[tt * NTAGS + lane];
            }
            cur ^= 1;
            __syncthreads();
        }
    }

    if (lane < NTAGS) term[lane] = fv[cur][lane] + trans[STOP_TAG * NTAGS + lane];
    __syncthreads();
    if (lane == 0) {
        float best = term[0];
        int bi = 0;
        for (int p = 1; p < NTAGS; ++p) {
            if (term[p] > best) { best = term[p]; bi = p; }
        }
        out[0] = best;
        int tag = bi;
        out[1 + (SEQ - 1)] = (float)tag;
        for (int t = SEQ - 1; t >= 1; --t) {
            tag = bp[t * NTAGS + tag];
            out[t] = (float)tag;  // out[1+(t-1)]
        }
    }
}

// ---------------------------------------------------------------------------
extern "C" void kernel_launch(void* const* d_in, const int* in_sizes, int n_in,
                              void* d_out, int out_size, void* d_ws, size_t ws_size,
                              hipStream_t stream) {
    const int* sent = (const int*)d_in[0];
    const float* emb = (const float*)d_in[1];
    const float* Wih0 = (const float*)d_in[2];
    const float* Whh0 = (const float*)d_in[3];
    const float* bih0 = (const float*)d_in[4];
    const float* bhh0 = (const float*)d_in[5];
    const float* Wih1 = (const float*)d_in[6];
    const float* Whh1 = (const float*)d_in[7];
    const float* bih1 = (const float*)d_in[8];
    const float* bhh1 = (const float*)d_in[9];
    const float* Wtag = (const float*)d_in[10];
    const float* btag = (const float*)d_in[11];
    const float* trans = (const float*)d_in[12];
    float* out = (float*)d_out;

    char* ws = (char*)d_ws;
    size_t off = 0;
    auto alloc = [&](size_t bytes) {
        void* p = ws + off;
        off += (bytes + 255) & ~(size_t)255;
        return p;
    };
    float* x0 = (float*)alloc(2048ull * 512 * 4);          // 4 MB
    float* Gi = (float*)alloc(2ull * 2048 * 2048 * 4);     // 32 MB (reused layer0/1)
    float* h0 = (float*)alloc(2ull * 2048 * 512 * 4);      // 8 MB
    float* h1 = (float*)alloc(2ull * 2048 * 512 * 4);      // 8 MB
    float* feats = (float*)alloc(2048ull * NTAGS * 4);

    // poison h buffers: "not yet written" sentinel for the data-polling sync
    hipMemsetAsync(h0, 0xAA, 2ull * 2048 * 512 * 4, stream);
    hipMemsetAsync(h1, 0xAA, 2ull * 2048 * 512 * 4, stream);

    k_embed<<<2048, 128, 0, stream>>>(sent, emb, x0);

    dim3 gg(32, 32, 2);
    // layer 0 input gates: Gi = x0 @ Wih0^T + bih0 + bhh0  (K=512)
    k_gemm<<<gg, 256, 0, stream>>>(x0, x0, Wih0, bih0, bhh0, Gi, 512);
    // layer 0 recurrence
    k_lstm<<<64, 256, 0, stream>>>(Whh0, Gi, h0);
    // layer 1 input gates: Gi = concat(h0f,h0b) @ Wih1^T + b  (K=1024)
    k_gemm<<<gg, 256, 0, stream>>>(h0, h0 + 2048ull * 512, Wih1, bih1, bhh1, Gi, 1024);
    // layer 1 recurrence
    k_lstm<<<64, 256, 0, stream>>>(Whh1, Gi, h1);
    // tag projection
    k_feats<<<2048, 64, 0, stream>>>(h1, Wtag, btag, feats);
    // viterbi decode
    k_viterbi<<<1, 64, 0, stream>>>(feats, trans, out);
}